// Round 2
// baseline (277.350 us; speedup 1.0000x reference)
//
#include <hip/hip_runtime.h>
#include <stdint.h>

static constexpr int kN = 128;
static constexpr int kTri = (kN * (kN - 1)) / 2;   // 8128 (BT scratch indexing)
static constexpr int kTriD = (kN * (kN + 1)) / 2;  // 8256 cells incl. diagonal
static constexpr int kThreads = 1024;
static constexpr float kNeg = -9999.0f;
static constexpr float kThresh = -9000.0f;
static constexpr float kArcBonus = 5.0f;
static constexpr int kDynLds = kTriD * 16;  // 132,096 B (one float4 quad per cell)
static constexpr int kCMax = 9;             // max row-cache slots per lane

__device__ __forceinline__ int rowBase(int i) { return (i * (2 * kN - 1 - i)) / 2; }
__device__ __forceinline__ int colBaseD(int c) { return (c * (c + 1)) / 2; }  // cells (r<=c, c)

// LDS-only workgroup barrier: orders LDS without draining vmcnt (wsBT stores
// and vL/vR prefetch loads stay in flight across steps).
__device__ __forceinline__ void ldsBarrier() {
    asm volatile("s_waitcnt lgkmcnt(0)\n\ts_barrier" ::: "memory");
}

template <int CTRL>
__device__ __forceinline__ float dppMax(float x) {
    const int y = __builtin_amdgcn_update_dpp(__float_as_int(x), __float_as_int(x),
                                              CTRL, 0xF, 0xF, true);
    return fmaxf(x, __int_as_float(y));
}
__device__ __forceinline__ float swzMax16(float x) {  // xor-16 within 32 lanes
    const int y = __builtin_amdgcn_ds_swizzle(__float_as_int(x), 0x401F);
    return fmaxf(x, __int_as_float(y));
}

// Static phase schedule (kN=128, 1024 threads): serial k<=16; P=8 k in [17,63];
// P=16 [64,95]; P=32 [96,111]; P=64 [112,127].
__device__ __forceinline__ int lpOf(int k) {
    if (k <= 16) return 0;
    if (k < 64) return 3;
    if (k < 96) return 4;
    if (k < 112) return 5;
    return 6;
}
__device__ __forceinline__ void mapStatic(int nk, int tid, int& i, int& j, bool& act) {
    const int lp = lpOf(nk);
    i = tid >> lp;
    j = i + nk;
    act = i < (kN - nk);
}

// Quad per cell: {x=s00, y=s11, z=s01, w=s10}, col-major incl. diagonal (diag=0).
// Serial-phase scan: both row and column quads from LDS (unchanged).
__device__ __forceinline__ void scanChunk(const float4* __restrict__ Q4,
                                          int i, int j, int k, int mlo, int mhi,
                                          float vL,
                                          float& bmax, int& ib,
                                          float& v01, int& i01,
                                          float& v11, int& i11) {
    const int qjb = colBaseD(j);  // + r => cell (r, j)
    int q, mstart;
    float4 cur;
    if (mlo == 0) {
        q = i + 1;
        cur = Q4[qjb + q];  // quad(i+1, j); diagonal zeros when k==1
        bmax = cur.z; ib = 0;   // base(0) = 0 + s01[i+1][j]
        const float p00 = (cur.z + vL) + kArcBonus;
        v01 = (p00 > kThresh) ? p00 : kNeg; i01 = 0;  // part00 seed
        mstart = 1;
    } else {
        q = i + mlo;
        cur = Q4[qjb + q];
        mstart = mlo;
    }
    int dA = colBaseD(q) + i;  // cell (i, q)
    int dInc = q + 1;          // colBaseD(q+1) - colBaseD(q)
#pragma unroll 8
    for (int m = mstart; m < mhi; ++m) {
        const float4 nxt = Q4[qjb + q + 1];  // quad(q+1, j); diag zeros at m==k-1
        const float4 diq = Q4[dA];           // quad(i, q)
        const float base = diq.y + nxt.z;    // s11[i][q] + s01[q+1][j]
        const float p01 = diq.z + cur.x;     // s01[i][q] + s00[q][j]
        const float p11 = diq.w + cur.y;     // s10[i][q] + s11[q][j]
        if (base > bmax) { bmax = base; ib = m; }  // strict > keeps earliest m
        if (p01 > v01) { v01 = p01; i01 = m; }
        if (p11 > v11) { v11 = p11; i11 = m; }
        cur = nxt;
        dA += dInc; ++dInc;
        ++q;
    }
}

__device__ __forceinline__ void writeCell(float4* __restrict__ Q4,
                                          uint32_t* __restrict__ wsBT,
                                          int i, int j, int k,
                                          float gb, int ib, float vLc, float vRc,
                                          float v01, int i01, float v11, int i11) {
    const float v00 = (gb + vLc) + kArcBonus;
    const float v10 = (gb + vRc) + kArcBonus;
    const float new10 = (v10 > kThresh) ? v10 : kNeg;
    if (new10 > v11) { v11 = new10; i11 = k; }  // q=j candidate; strict > keeps earlier q
    float4 w = make_float4(kNeg, kNeg, kNeg, kNeg);
    uint32_t p = 0;
    if (v00 > kThresh) { w.x = v00; p |= (uint32_t)(i + ib); }
    if (v01 > kThresh) { w.z = v01; p |= (uint32_t)(i + i01) << 8; }
    if (v10 > kThresh) { w.w = v10; p |= (uint32_t)(i + ib) << 16; }
    if (v11 > kThresh) { w.y = v11; p |= (uint32_t)(i + i11) << 24; }
    Q4[colBaseD(j) + i] = w;          // one ds_write_b128
    wsBT[rowBase(i) + k - 1] = p;     // lone global store; not drained per step
}

// Serial step (k<=16): one thread per cell.
__device__ __forceinline__ void doStepSerial(int k, int tid,
                                             float4* __restrict__ Q4,
                                             uint32_t* __restrict__ wsBT,
                                             const float* __restrict__ v,
                                             int& ci, int& cj, bool& cact,
                                             float& vL, float& vR) {
    const int i = ci, j = cj;
    const bool act = cact;
    const float vLc = vL, vRc = vR;
    float bmax = -3.0e38f, v01 = -3.0e38f, v11 = -3.0e38f;
    int ib = 0, i01 = 0, i11 = 0x7FFFFFFF;
    if (act) {
        scanChunk(Q4, i, j, k, 0, k, vLc, bmax, ib, v01, i01, v11, i11);
    }
    if (k + 1 < kN) {
        mapStatic(k + 1, tid, ci, cj, cact);
        vL = cact ? v[cj * kN + ci] : 0.f;
        vR = cact ? v[ci * kN + cj] : 0.f;
    }
    if (act) {
        writeCell(Q4, wsBT, i, j, k, bmax, ib, vLc, vRc, v01, i01, v11, i11);
    }
}

// ---- Chunked phases: register row-cache + register column-prefetch ----
// Within a phase, i = tid>>LP is FIXED and chart cells are write-once.
//  * Row operands {s11,s01,s10}(i, i+m): preloaded once per phase; the fresh
//    slot m=k-1 is the cell THIS group computed last step -- after the
//    butterfly every lane holds the group max, so it lives in registers
//    (fw11/fw01/fw10). Zero row LDS reads in steady state.
//  * Column quads (q, j) for step k+1: all from steps <= k-1 (visible since
//    the PREVIOUS barrier) except (i+1, j+1) [written at step k]. So the
//    whole window is prefetched into col[] BEFORE the barrier (overlapping
//    the reduction tail); only l==0 lanes read the single fresh quad
//    post-barrier. Earliest-q tie-break preserved by >= merges of the
//    deferred m=0/m=1 contributions after the strict-> loop.
template <int LP, int C>
__device__ __forceinline__ void preloadRow(int k0, int tid,
                                           const float4* __restrict__ Q4,
                                           float (&r11)[kCMax], float (&r01)[kCMax],
                                           float (&r10)[kCMax]) {
    constexpr int P = 1 << LP;
    const int i = tid >> LP;
    const int l = tid & (P - 1);
    const int mlo = l * C;
    const int mstart = mlo ? mlo : 1;
    const bool act = i < (kN - k0);
#pragma unroll
    for (int c = 0; c < C; ++c) {
        const int m = mstart + c;
        if (act && (m < mlo + C) && (m <= k0 - 1)) {  // incl. m=k0-1 (visible here)
            const float4 d = Q4[colBaseD(i + m) + i];  // quad(i, i+m), immutable
            r11[c] = d.y; r01[c] = d.z; r10[c] = d.w;
        }
    }
}

// Seed fw from the preloaded row slot m = k0-1 so the first step's isF-merge
// is a no-op (same value). Only the owning lane's fw matters.
template <int LP, int C>
__device__ __forceinline__ void fwInit(int k0, int tid,
                                       const float (&r11)[kCMax], const float (&r01)[kCMax],
                                       const float (&r10)[kCMax],
                                       float& fw11, float& fw01, float& fw10) {
    constexpr int P = 1 << LP;
    const int l = tid & (P - 1);
    const int mlo = l * C;
    const int mstart = mlo ? mlo : 1;
#pragma unroll
    for (int c = 0; c < C; ++c) {
        if (mstart + c == k0 - 1) { fw11 = r11[c]; fw01 = r01[c]; fw10 = r10[c]; }
    }
}

// Phase-entry column prefetch (post-barrier: everything visible, incl. c=0).
template <int LP, int C>
__device__ __forceinline__ void prefetchColEntry(int k, int tid,
                                                 const float4* __restrict__ Q4,
                                                 float4 (&col)[kCMax + 1]) {
    constexpr int P = 1 << LP;
    const int i = tid >> LP;
    const int l = tid & (P - 1);
    const int mlo = l * C;
    const int mstart = mlo ? mlo : 1;
    const bool act = i < (kN - k);
    const int qjb = colBaseD(i + k);
#pragma unroll
    for (int c = 0; c <= C; ++c) {
        int addr = qjb + i + mstart + c;
        if (addr > kTriD - 1) addr = kTriD - 1;  // clamp tail-lane overread
        if (act) col[c] = Q4[addr];
    }
}

template <int LP, int C>
__device__ __forceinline__ void doStepC(int k, int tid, int laneId,
                                        float4* __restrict__ Q4,
                                        uint32_t* __restrict__ wsBT,
                                        const float* __restrict__ v,
                                        int& ci, int& cj, bool& cact,
                                        float& vL, float& vR,
                                        float (&r11)[kCMax], float (&r01)[kCMax],
                                        float (&r10)[kCMax],
                                        float4 (&col)[kCMax + 1],
                                        float& fw11, float& fw01, float& fw10,
                                        bool c0valid, bool prefetchNext) {
    constexpr int P = 1 << LP;
    const int i = ci, j = cj;
    const bool act = cact;
    const float vLc = vL, vRc = vR;  // prefetch below overwrites vL/vR
    const int l = tid & (P - 1);
    const int mlo = l * C;
    const int mstart = mlo ? mlo : 1;
    const int mhi = (mlo + C < k) ? (mlo + C) : k;
    const bool waveActive = (((tid & ~63) >> LP) < (kN - k));  // wave-uniform
    const int qjb = colBaseD(j);
    const int mf = k - 1;

    // Post-barrier fresh column quad (i+1, j): only needed by l==0 lanes, only
    // in steady state (phase entry prefetched it). Issued first; its latency
    // overlaps the register-only compute below.
    if (!c0valid) {
        if (l == 0 && act) col[0] = Q4[qjb + i + 1];
    }

    float bmax = -3.0e38f, v01 = -3.0e38f, v11 = -3.0e38f;
    int ib = 0x7FFFFFFF, i01 = 0x7FFFFFFF, i11 = 0x7FFFFFFF;

    const bool lact = waveActive && act && (mstart < mhi);

    if (c0valid && act && mlo == 0) {  // original order: seed then strict->
        bmax = col[0].z; ib = 0;       // base(0) = 0 + s01[i+1][j]
        const float p00 = (col[0].z + vLc) + kArcBonus;
        v01 = (p00 > kThresh) ? p00 : kNeg; i01 = 0;  // part00 seed
    }
    const bool deferM1 = (!c0valid) && (mlo == 0);  // m=0/m=1 merged after loop
#pragma unroll
    for (int c = 0; c < C; ++c) {
        const int m = mstart + c;
        // Row operands: registers; fresh slot m==k-1 comes from fw (the cell
        // this group computed last step), committed into the cache here.
        const bool isF = (m == mf);
        const float a11 = isF ? fw11 : r11[c];
        const float a01 = isF ? fw01 : r01[c];
        const float a10 = isF ? fw10 : r10[c];
        r11[c] = a11; r01[c] = a01; r10[c] = a10;
        const bool on = lact && (m < mhi) && !(deferM1 && c == 0);
        if (on) {
            const float base = a11 + col[c + 1].z;  // s11[i][q] + s01[q+1][j]
            const float p01v = a01 + col[c].x;      // s01[i][q] + s00[q][j]
            const float p11v = a10 + col[c].y;      // s10[i][q] + s11[q][j]
            if (base > bmax) { bmax = base; ib = m; }  // strict > keeps earliest m
            if (p01v > v01) { v01 = p01v; i01 = m; }
            if (p11v > v11) { v11 = p11v; i11 = m; }
        }
    }
    if (deferM1 && act) {
        // m=1 contributions (p01/p11 need the fresh quad), then the m=0 seed;
        // >= merges keep the earlier index on ties.
        const float base1 = r11[0] + col[1].z;
        if (base1 >= bmax) { bmax = base1; ib = 1; }
        const float p011 = r01[0] + col[0].x;
        if (p011 >= v01) { v01 = p011; i01 = 1; }
        const float p111 = r10[0] + col[0].y;
        if (p111 >= v11) { v11 = p111; i11 = 1; }
        const float sb = col[0].z;
        if (sb >= bmax) { bmax = sb; ib = 0; }
        const float p00 = (sb + vLc) + kArcBonus;
        const float sp = (p00 > kThresh) ? p00 : kNeg;
        if (sp >= v01) { v01 = sp; i01 = 0; }
    }

    // Next-step mapping + vL/vR prefetch (overlaps reduction + barrier).
    if (k + 1 < kN) {
        mapStatic(k + 1, tid, ci, cj, cact);
        vL = cact ? v[cj * kN + ci] : 0.f;
        vR = cact ? v[ci * kN + cj] : 0.f;
    }

    // Column prefetch for step k+1 (same phase => same i/l/mstart, column j+1).
    // All target cells are from steps <= k-1 (visible since the PREVIOUS
    // barrier) except (i+1, j+1) [being written this step] == slot c=0 of
    // l==0, which is skipped and read post-barrier next step. No race: step-k
    // writers only touch width-k cells.
    if (prefetchNext) {
        const int qjb2 = qjb + j + 1;  // colBaseD(j+1)
#pragma unroll
        for (int c = 0; c <= C; ++c) {
            const bool skip = (mlo == 0 && c == 0);
            int addr = qjb2 + i + mstart + c;
            if (addr > kTriD - 1) addr = kTriD - 1;
            if (cact && !skip) col[c] = Q4[addr];
        }
    }

    if (waveActive) {
        // compile-time butterfly: xor1, xor2, mirror8 [, mirror16][, xor16][, xor32]
        float gB = dppMax<0x141>(dppMax<0x4E>(dppMax<0xB1>(bmax)));
        float g01 = dppMax<0x141>(dppMax<0x4E>(dppMax<0xB1>(v01)));
        float g11 = dppMax<0x141>(dppMax<0x4E>(dppMax<0xB1>(v11)));
        if constexpr (P >= 16) {
            gB = dppMax<0x140>(gB); g01 = dppMax<0x140>(g01); g11 = dppMax<0x140>(g11);
        }
        if constexpr (P >= 32) {
            gB = swzMax16(gB); g01 = swzMax16(g01); g11 = swzMax16(g11);
        }
        if constexpr (P == 64) {
            gB = fmaxf(gB, __shfl_xor(gB, 32, 64));
            g01 = fmaxf(g01, __shfl_xor(g01, 32, 64));
            g11 = fmaxf(g11, __shfl_xor(g11, 32, 64));
        }
        // earliest-m via ballot (contiguous chunks => lane order == m order;
        // empty lanes hold -3e38, can never equal group max)
        const int grpStart = laneId & ~(P - 1);
        const uint64_t gmask =
            (P == 64) ? ~0ull : (((1ull << P) - 1ull) << grpStart);
        const uint64_t mB = __ballot(bmax == gB) & gmask;
        const uint64_t m2 = __ballot(v01 == g01) & gmask;
        const uint64_t m3 = __ballot(v11 == g11) & gmask;
        const int rB = __shfl(ib, __ffsll((unsigned long long)mB) - 1, 64);
        const int rq01 = __shfl(i01, __ffsll((unsigned long long)m2) - 1, 64);
        const int rq11 = __shfl(i11, __ffsll((unsigned long long)m3) - 1, 64);

        // All lanes now hold the group's written-cell values: keep the row-
        // operand triple in registers for next step's fresh slot (m = k).
        const float v00f = (gB + vLc) + kArcBonus;
        const float v10f = (gB + vRc) + kArcBonus;
        const float new10 = (v10f > kThresh) ? v10f : kNeg;
        float v11m = g11;
        if (new10 > v11m) v11m = new10;
        fw11 = (v11m > kThresh) ? v11m : kNeg;  // w.y = s11(i,j)
        fw01 = (g01 > kThresh) ? g01 : kNeg;    // w.z = s01(i,j)
        fw10 = (v10f > kThresh) ? v10f : kNeg;  // w.w = s10(i,j)

        if (act && l == 0) {
            writeCell(Q4, wsBT, i, j, k, gB, rB, vLc, vRc, g01, rq01, g11, rq11);
        }
    }
}

__global__ __launch_bounds__(kThreads) void eisner_dp(
    const float* __restrict__ vinfo,  // [B][N][N] fp32
    float* __restrict__ outS,         // [B][N][N][2][2] fp32 scores
    float* __restrict__ outBT,        // [B][N][N][2][2] fp32 backtrace (integer-valued)
    uint32_t* __restrict__ btPacked)  // [B][kTri] packed backtrace bytes (d_ws)
{
    extern __shared__ float4 Q4[];

    const int tid = threadIdx.x;
    const int laneId = tid & 63;
    const int b = blockIdx.x;
    const float* v = vinfo + (size_t)b * kN * kN;
    uint32_t* wsBT = btPacked + (size_t)b * kTri;

    // Diagonal quads = 0. Off-diagonal cells need no init (written before read).
    const float4 zeroq = make_float4(0.f, 0.f, 0.f, 0.f);
    if (tid < kN) Q4[colBaseD(tid) + tid] = zeroq;

    // Register caches.
    float r11[kCMax], r01[kCMax], r10[kCMax];
    float4 col[kCMax + 1];
    float fw11 = kNeg, fw01 = kNeg, fw10 = kNeg;
#pragma unroll
    for (int c = 0; c < kCMax; ++c) { r11[c] = kNeg; r01[c] = kNeg; r10[c] = kNeg; }
#pragma unroll
    for (int c = 0; c <= kCMax; ++c) col[c] = zeroq;

    // Prefetch step-1 mapping + vL/vR.
    int ci, cj; bool cact;
    mapStatic(1, tid, ci, cj, cact);
    float vL = cact ? v[cj * kN + ci] : 0.f;
    float vR = cact ? v[ci * kN + cj] : 0.f;
    __syncthreads();

    for (int k = 1; k <= 16; ++k) {
        doStepSerial(k, tid, Q4, wsBT, v, ci, cj, cact, vL, vR);
        ldsBarrier();
    }
    // P=8 phase split: C=5 while k<40, C=9 after. Odd C => conflict-free cols.
    preloadRow<3, 5>(17, tid, Q4, r11, r01, r10);
    fwInit<3, 5>(17, tid, r11, r01, r10, fw11, fw01, fw10);
    prefetchColEntry<3, 5>(17, tid, Q4, col);
    for (int k = 17; k < 40; ++k) {
        doStepC<3, 5>(k, tid, laneId, Q4, wsBT, v, ci, cj, cact, vL, vR,
                      r11, r01, r10, col, fw11, fw01, fw10, k == 17, k + 1 < 40);
        ldsBarrier();
    }
    preloadRow<3, 9>(40, tid, Q4, r11, r01, r10);
    fwInit<3, 9>(40, tid, r11, r01, r10, fw11, fw01, fw10);
    prefetchColEntry<3, 9>(40, tid, Q4, col);
    for (int k = 40; k < 64; ++k) {
        doStepC<3, 9>(k, tid, laneId, Q4, wsBT, v, ci, cj, cact, vL, vR,
                      r11, r01, r10, col, fw11, fw01, fw10, k == 40, k + 1 < 64);
        ldsBarrier();
    }
    preloadRow<4, 7>(64, tid, Q4, r11, r01, r10);  // 16*7=112 >= 95
    fwInit<4, 7>(64, tid, r11, r01, r10, fw11, fw01, fw10);
    prefetchColEntry<4, 7>(64, tid, Q4, col);
    for (int k = 64; k < 96; ++k) {
        doStepC<4, 7>(k, tid, laneId, Q4, wsBT, v, ci, cj, cact, vL, vR,
                      r11, r01, r10, col, fw11, fw01, fw10, k == 64, k + 1 < 96);
        ldsBarrier();
    }
    preloadRow<5, 5>(96, tid, Q4, r11, r01, r10);  // 32*5=160 >= 111
    fwInit<5, 5>(96, tid, r11, r01, r10, fw11, fw01, fw10);
    prefetchColEntry<5, 5>(96, tid, Q4, col);
    for (int k = 96; k < 112; ++k) {
        doStepC<5, 5>(k, tid, laneId, Q4, wsBT, v, ci, cj, cact, vL, vR,
                      r11, r01, r10, col, fw11, fw01, fw10, k == 96, k + 1 < 112);
        ldsBarrier();
    }
    preloadRow<6, 3>(112, tid, Q4, r11, r01, r10);  // 64*3=192 >= 127
    fwInit<6, 3>(112, tid, r11, r01, r10, fw11, fw01, fw10);
    prefetchColEntry<6, 3>(112, tid, Q4, col);
    for (int k = 112; k < 128; ++k) {
        doStepC<6, 3>(k, tid, laneId, Q4, wsBT, v, ci, cj, cact, vL, vR,
                      r11, r01, r10, col, fw11, fw01, fw10, k == 112, k + 1 < 128);
        ldsBarrier();
    }

    // Full barrier (drains vmcnt) before reading wsBT back.
    __syncthreads();

    // ---- epilogue: emit full [N][N][2][2] scores + backtrace, coalesced ----
    float4* gS4 = (float4*)(outS + (size_t)b * kN * kN * 4);
    float4* gB4 = (float4*)(outBT + (size_t)b * kN * kN * 4);
    const float4 negq = make_float4(kNeg, kNeg, kNeg, kNeg);
    for (int c = tid; c < kN * kN; c += kThreads) {
        const int i = c >> 7, j = c & (kN - 1);
        if (i < j) {
            const float4 q = Q4[colBaseD(j) + i];
            gS4[c] = make_float4(q.x, q.z, q.w, q.y);  // {s00, s01, s10, s11}
            const uint32_t p = wsBT[rowBase(i) + (j - i - 1)];
            gB4[c] = make_float4((float)(p & 255u), (float)((p >> 8) & 255u),
                                 (float)((p >> 16) & 255u), (float)(p >> 24));
        } else if (i == j) {
            gS4[c] = zeroq;
            gB4[c] = zeroq;
        } else {
            gS4[c] = negq;
            gB4[c] = zeroq;
        }
    }
}

extern "C" void kernel_launch(void* const* d_in, const int* in_sizes, int n_in,
                              void* d_out, int out_size, void* d_ws, size_t ws_size,
                              hipStream_t stream) {
    (void)n_in; (void)out_size; (void)ws_size;
    const float* vinfo = (const float*)d_in[0];  // fp32 [B][N][N]
    const int B = in_sizes[1];                   // b_buffer_size has B elements
    float* outS = (float*)d_out;
    float* outBT = outS + (size_t)B * kN * kN * 4;
    uint32_t* btPacked = (uint32_t*)d_ws;        // needs B*kTri*4 = ~2.1 MB

    hipFuncSetAttribute(reinterpret_cast<const void*>(eisner_dp),
                        hipFuncAttributeMaxDynamicSharedMemorySize, kDynLds);

    eisner_dp<<<dim3(B), dim3(kThreads), kDynLds, stream>>>(vinfo, outS, outBT, btPacked);
}

// Round 3
// 244.859 us; speedup vs baseline: 1.1327x; 1.1327x over previous
//
#include <hip/hip_runtime.h>
#include <stdint.h>

static constexpr int kN = 128;
static constexpr int kTri = (kN * (kN - 1)) / 2;   // 8128 (BT scratch indexing)
static constexpr int kTriD = (kN * (kN + 1)) / 2;  // 8256 cells incl. diagonal
static constexpr int kThreads = 1024;
static constexpr float kNeg = -9999.0f;
static constexpr float kThresh = -9000.0f;
static constexpr float kArcBonus = 5.0f;
static constexpr int kDynLds = kTriD * 16;  // 132,096 B (one float4 quad per cell)
static constexpr int kCMax = 9;             // max row-cache slots per lane

__device__ __forceinline__ int rowBase(int i) { return (i * (2 * kN - 1 - i)) / 2; }
__device__ __forceinline__ int colBaseD(int c) { return (c * (c + 1)) / 2; }  // cells (r<=c, c)

// LDS-only workgroup barrier: orders LDS without draining vmcnt (wsBT stores
// and vL/vR prefetch loads stay in flight across steps).
__device__ __forceinline__ void ldsBarrier() {
    asm volatile("s_waitcnt lgkmcnt(0)\n\ts_barrier" ::: "memory");
}

template <int CTRL>
__device__ __forceinline__ float dppMax(float x) {
    const int y = __builtin_amdgcn_update_dpp(__float_as_int(x), __float_as_int(x),
                                              CTRL, 0xF, 0xF, true);
    return fmaxf(x, __int_as_float(y));
}
__device__ __forceinline__ float swzMax16(float x) {  // xor-16 within 32 lanes
    const int y = __builtin_amdgcn_ds_swizzle(__float_as_int(x), 0x401F);
    return fmaxf(x, __int_as_float(y));
}

// Static phase schedule (kN=128, 1024 threads): serial k<=16; P=8 k in [17,63];
// P=16 [64,95]; P=32 [96,111]; P=64 [112,127].
__device__ __forceinline__ int lpOf(int k) {
    if (k <= 16) return 0;
    if (k < 64) return 3;
    if (k < 96) return 4;
    if (k < 112) return 5;
    return 6;
}
__device__ __forceinline__ void mapStatic(int nk, int tid, int& i, int& j, bool& act) {
    const int lp = lpOf(nk);
    i = tid >> lp;
    j = i + nk;
    act = i < (kN - nk);
}

// Quad per cell: {x=s00, y=s11, z=s01, w=s10}, col-major incl. diagonal (diag=0).
// Returns the stored quad so callers can mirror it into registers.
__device__ __forceinline__ float4 writeCell(float4* __restrict__ Q4,
                                            uint32_t* __restrict__ wsBT,
                                            int i, int j, int k,
                                            float gb, int ib, float vLc, float vRc,
                                            float v01, int i01, float v11, int i11) {
    const float v00 = (gb + vLc) + kArcBonus;
    const float v10 = (gb + vRc) + kArcBonus;
    const float new10 = (v10 > kThresh) ? v10 : kNeg;
    if (new10 > v11) { v11 = new10; i11 = k; }  // q=j candidate; strict > keeps earlier q
    float4 w = make_float4(kNeg, kNeg, kNeg, kNeg);
    uint32_t p = 0;
    if (v00 > kThresh) { w.x = v00; p |= (uint32_t)(i + ib); }
    if (v01 > kThresh) { w.z = v01; p |= (uint32_t)(i + i01) << 8; }
    if (v10 > kThresh) { w.w = v10; p |= (uint32_t)(i + ib) << 16; }
    if (v11 > kThresh) { w.y = v11; p |= (uint32_t)(i + i11) << 24; }
    Q4[colBaseD(j) + i] = w;          // one ds_write_b128
    wsBT[rowBase(i) + k - 1] = p;     // lone global store; not drained per step
    return w;
}

// Serial step (k<=16), k is COMPILE-TIME (caller loop unrolled): one thread per
// cell, i = tid fixed across the whole serial phase, so all row operands
// {s11,s01,s10}(i, i+m) are this thread's OWN previous outputs, mirrored in
// sr[] registers. Only the column stream (other threads' cells) reads LDS,
// with base+immediate-offset addressing.
__device__ __forceinline__ void doStepSerialReg(int k, int tid,
                                                float4* __restrict__ Q4,
                                                uint32_t* __restrict__ wsBT,
                                                const float* __restrict__ v,
                                                int& ci, int& cj, bool& cact,
                                                float& vL, float& vR,
                                                float (&sr11)[17], float (&sr01)[17],
                                                float (&sr10)[17]) {
    const int i = ci, j = cj;
    const bool act = cact;
    const float vLc = vL, vRc = vR;
    float bmax = -3.0e38f, v01 = -3.0e38f, v11 = -3.0e38f;
    int ib = 0, i01 = 0, i11 = 0x7FFFFFFF;
    if (act) {
        const int qjb = colBaseD(j);
        float4 cur = Q4[qjb + i + 1];  // quad(i+1, j); diagonal zeros when k==1
        bmax = cur.z; ib = 0;          // base(0) = 0 + s01[i+1][j]
        const float p00 = (cur.z + vLc) + kArcBonus;
        v01 = (p00 > kThresh) ? p00 : kNeg; i01 = 0;  // part00 seed
#pragma unroll
        for (int m = 1; m < 16; ++m) {
            if (m < k) {  // compile-time when k is constant-folded
                const float4 nxt = Q4[qjb + i + m + 1];  // quad(q+1, j)
                const float base = sr11[m] + nxt.z;      // s11[i][q] + s01[q+1][j]
                const float p01v = sr01[m] + cur.x;      // s01[i][q] + s00[q][j]
                const float p11v = sr10[m] + cur.y;      // s10[i][q] + s11[q][j]
                if (base > bmax) { bmax = base; ib = m; }  // strict > keeps earliest m
                if (p01v > v01) { v01 = p01v; i01 = m; }
                if (p11v > v11) { v11 = p11v; i11 = m; }
                cur = nxt;
            }
        }
    }
    if (k + 1 < kN) {
        mapStatic(k + 1, tid, ci, cj, cact);
        vL = cact ? v[cj * kN + ci] : 0.f;
        vR = cact ? v[ci * kN + cj] : 0.f;
    }
    if (act) {
        const float4 w = writeCell(Q4, wsBT, i, j, k, bmax, ib, vLc, vRc,
                                   v01, i01, v11, i11);
        sr11[k] = w.y; sr01[k] = w.z; sr10[k] = w.w;  // constant index (k unrolled)
    }
}

// ---- Chunked phases: register row-cache + fw forwarding ----
// Within a phase, i = tid>>LP is FIXED and chart cells are write-once.
//  * Row operands {s11,s01,s10}(i, i+m): preloaded once per phase into r[].
//  * The fresh slot m = k-1 is the cell THIS group computed last step: after
//    the butterfly every lane holds the group max, so it lives in registers
//    (fw11/fw01/fw10). ZERO row LDS reads in steady state.
//  * Column stream unchanged from the verified R1 structure (chained reads,
//    guarded by m < mhi).
template <int LP, int C>
__device__ __forceinline__ void preloadRow(int k0, int tid,
                                           const float4* __restrict__ Q4,
                                           float (&r11)[kCMax], float (&r01)[kCMax],
                                           float (&r10)[kCMax]) {
    constexpr int P = 1 << LP;
    const int i = tid >> LP;
    const int l = tid & (P - 1);
    const int mlo = l * C;
    const int mstart = mlo ? mlo : 1;
    const bool act = i < (kN - k0);
#pragma unroll
    for (int c = 0; c < C; ++c) {
        const int m = mstart + c;
        if (act && (m < mlo + C) && (m <= k0 - 1)) {  // incl. m=k0-1 (visible here)
            const float4 d = Q4[colBaseD(i + m) + i];  // quad(i, i+m), immutable
            r11[c] = d.y; r01[c] = d.z; r10[c] = d.w;
        }
    }
    // Slots with m > k0-1 stay stale: first read only at step k=m+1, where the
    // isF path substitutes fw and commits it -- stale value never consumed.
}

// Seed fw from the preloaded row slot m = k0-1 (only the owning lane's fw
// matters at the first step of a phase).
template <int LP, int C>
__device__ __forceinline__ void fwInit(int k0, int tid,
                                       const float (&r11)[kCMax], const float (&r01)[kCMax],
                                       const float (&r10)[kCMax],
                                       float& fw11, float& fw01, float& fw10) {
    constexpr int P = 1 << LP;
    const int l = tid & (P - 1);
    const int mlo = l * C;
    const int mstart = mlo ? mlo : 1;
#pragma unroll
    for (int c = 0; c < C; ++c) {
        if (mstart + c == k0 - 1) { fw11 = r11[c]; fw01 = r01[c]; fw10 = r10[c]; }
    }
}

template <int LP, int C>
__device__ __forceinline__ void doStepC(int k, int tid, int laneId,
                                        float4* __restrict__ Q4,
                                        uint32_t* __restrict__ wsBT,
                                        const float* __restrict__ v,
                                        int& ci, int& cj, bool& cact,
                                        float& vL, float& vR,
                                        float (&r11)[kCMax], float (&r01)[kCMax],
                                        float (&r10)[kCMax],
                                        float& fw11, float& fw01, float& fw10) {
    constexpr int P = 1 << LP;
    const int i = ci, j = cj;
    const bool act = cact;
    const float vLc = vL, vRc = vR;  // prefetch below overwrites vL/vR
    const int l = tid & (P - 1);
    const int mlo = l * C;
    const int mstart = mlo ? mlo : 1;
    const int mhi = (mlo + C < k) ? (mlo + C) : k;
    const bool waveActive = (((tid & ~63) >> LP) < (kN - k));  // wave-uniform

    float bmax = -3.0e38f, v01 = -3.0e38f, v11 = -3.0e38f;
    int ib = 0x7FFFFFFF, i01 = 0x7FFFFFFF, i11 = 0x7FFFFFFF;

    const int mf = k - 1;
    const bool lact = waveActive && act && (mstart < mhi);
    const int qjb = colBaseD(j);
    float4 cur = make_float4(0.f, 0.f, 0.f, 0.f);
    if (lact) cur = Q4[qjb + i + mstart];  // column seed quad(i+mstart, j)
    if (act && mlo == 0) {
        bmax = cur.z; ib = 0;  // base(0) = 0 + s01[i+1][j]
        const float p00 = (cur.z + vLc) + kArcBonus;
        v01 = (p00 > kThresh) ? p00 : kNeg; i01 = 0;  // part00 seed
    }
#pragma unroll
    for (int c = 0; c < C; ++c) {
        const int m = mstart + c;
        // Row operands: registers; fresh slot m==k-1 comes from fw (the cell
        // this group computed last step), committed into the cache here.
        const bool isF = (m == mf);
        const float a11 = isF ? fw11 : r11[c];
        const float a01 = isF ? fw01 : r01[c];
        const float a10 = isF ? fw10 : r10[c];
        r11[c] = a11; r01[c] = a01; r10[c] = a10;
        const bool on = lact && (m < mhi);
        if (on) {
            const float4 nxt = Q4[qjb + i + m + 1];  // quad(q+1, j); compile-time offset
            const float base = a11 + nxt.z;          // s11[i][q] + s01[q+1][j]
            const float p01v = a01 + cur.x;          // s01[i][q] + s00[q][j]
            const float p11v = a10 + cur.y;          // s10[i][q] + s11[q][j]
            if (base > bmax) { bmax = base; ib = m; }  // strict > keeps earliest m
            if (p01v > v01) { v01 = p01v; i01 = m; }
            if (p11v > v11) { v11 = p11v; i11 = m; }
            cur = nxt;
        }
    }

    // Prefetch next step's mapping + vL/vR (overlaps reduction + barrier).
    if (k + 1 < kN) {
        mapStatic(k + 1, tid, ci, cj, cact);
        vL = cact ? v[cj * kN + ci] : 0.f;
        vR = cact ? v[ci * kN + cj] : 0.f;
    }

    if (waveActive) {
        // compile-time butterfly: xor1, xor2, mirror8 [, mirror16][, xor16][, xor32]
        float gB = dppMax<0x141>(dppMax<0x4E>(dppMax<0xB1>(bmax)));
        float g01 = dppMax<0x141>(dppMax<0x4E>(dppMax<0xB1>(v01)));
        float g11 = dppMax<0x141>(dppMax<0x4E>(dppMax<0xB1>(v11)));
        if constexpr (P >= 16) {
            gB = dppMax<0x140>(gB); g01 = dppMax<0x140>(g01); g11 = dppMax<0x140>(g11);
        }
        if constexpr (P >= 32) {
            gB = swzMax16(gB); g01 = swzMax16(g01); g11 = swzMax16(g11);
        }
        if constexpr (P == 64) {
            gB = fmaxf(gB, __shfl_xor(gB, 32, 64));
            g01 = fmaxf(g01, __shfl_xor(g01, 32, 64));
            g11 = fmaxf(g11, __shfl_xor(g11, 32, 64));
        }
        // earliest-m via ballot (contiguous chunks => lane order == m order;
        // empty lanes hold -3e38, can never equal group max)
        const int grpStart = laneId & ~(P - 1);
        const uint64_t gmask =
            (P == 64) ? ~0ull : (((1ull << P) - 1ull) << grpStart);
        const uint64_t mB = __ballot(bmax == gB) & gmask;
        const uint64_t m2 = __ballot(v01 == g01) & gmask;
        const uint64_t m3 = __ballot(v11 == g11) & gmask;
        const int rB = __shfl(ib, __ffsll((unsigned long long)mB) - 1, 64);
        const int rq01 = __shfl(i01, __ffsll((unsigned long long)m2) - 1, 64);
        const int rq11 = __shfl(i11, __ffsll((unsigned long long)m3) - 1, 64);

        // All lanes now hold the group's written-cell values: keep the row-
        // operand triple in registers for next step's fresh slot (m = k).
        // Identical arithmetic to writeCell => bitwise-equal values.
        const float v00f = (gB + vLc) + kArcBonus;
        const float v10f = (gB + vRc) + kArcBonus;
        const float new10 = (v10f > kThresh) ? v10f : kNeg;
        float v11m = g11;
        if (new10 > v11m) v11m = new10;
        fw11 = (v11m > kThresh) ? v11m : kNeg;  // w.y = s11(i,j)
        fw01 = (g01 > kThresh) ? g01 : kNeg;    // w.z = s01(i,j)
        fw10 = (v10f > kThresh) ? v10f : kNeg;  // w.w = s10(i,j)
        (void)v00f;

        if (act && l == 0) {
            writeCell(Q4, wsBT, i, j, k, gB, rB, vLc, vRc, g01, rq01, g11, rq11);
        }
    }
}

__global__ __launch_bounds__(kThreads) void eisner_dp(
    const float* __restrict__ vinfo,  // [B][N][N] fp32
    float* __restrict__ outS,         // [B][N][N][2][2] fp32 scores
    float* __restrict__ outBT,        // [B][N][N][2][2] fp32 backtrace (integer-valued)
    uint32_t* __restrict__ btPacked)  // [B][kTri] packed backtrace bytes (d_ws)
{
    extern __shared__ float4 Q4[];

    const int tid = threadIdx.x;
    const int laneId = tid & 63;
    const int b = blockIdx.x;
    const float* v = vinfo + (size_t)b * kN * kN;
    uint32_t* wsBT = btPacked + (size_t)b * kTri;

    // Diagonal quads = 0. Off-diagonal cells need no init (written before read).
    const float4 zeroq = make_float4(0.f, 0.f, 0.f, 0.f);
    if (tid < kN) Q4[colBaseD(tid) + tid] = zeroq;

    // Prefetch step-1 mapping + vL/vR.
    int ci, cj; bool cact;
    mapStatic(1, tid, ci, cj, cact);
    float vL = cact ? v[cj * kN + ci] : 0.f;
    float vR = cact ? v[ci * kN + cj] : 0.f;
    __syncthreads();

    // ---- serial phase (k = 1..16), fully unrolled so sr indices are constant;
    // own-row operands live entirely in registers ----
    {
        float sr11[17], sr01[17], sr10[17];
#pragma unroll
        for (int k = 1; k <= 16; ++k) {
            doStepSerialReg(k, tid, Q4, wsBT, v, ci, cj, cact, vL, vR,
                            sr11, sr01, sr10);
            ldsBarrier();
        }
    }

    // Row caches (registers); slots filled by preloadRow + fw commits.
    float r11[kCMax], r01[kCMax], r10[kCMax];
    float fw11 = kNeg, fw01 = kNeg, fw10 = kNeg;
#pragma unroll
    for (int c = 0; c < kCMax; ++c) { r11[c] = kNeg; r01[c] = kNeg; r10[c] = kNeg; }

    // P=8 phase split: C=5 while k<40, C=9 after. Odd C => conflict-free cols.
    preloadRow<3, 5>(17, tid, Q4, r11, r01, r10);
    fwInit<3, 5>(17, tid, r11, r01, r10, fw11, fw01, fw10);
    for (int k = 17; k < 40; ++k) {
        doStepC<3, 5>(k, tid, laneId, Q4, wsBT, v, ci, cj, cact, vL, vR,
                      r11, r01, r10, fw11, fw01, fw10);
        ldsBarrier();
    }
    preloadRow<3, 9>(40, tid, Q4, r11, r01, r10);
    fwInit<3, 9>(40, tid, r11, r01, r10, fw11, fw01, fw10);
    for (int k = 40; k < 64; ++k) {
        doStepC<3, 9>(k, tid, laneId, Q4, wsBT, v, ci, cj, cact, vL, vR,
                      r11, r01, r10, fw11, fw01, fw10);
        ldsBarrier();
    }
    preloadRow<4, 7>(64, tid, Q4, r11, r01, r10);  // 16*7=112 >= 95
    fwInit<4, 7>(64, tid, r11, r01, r10, fw11, fw01, fw10);
    for (int k = 64; k < 96; ++k) {
        doStepC<4, 7>(k, tid, laneId, Q4, wsBT, v, ci, cj, cact, vL, vR,
                      r11, r01, r10, fw11, fw01, fw10);
        ldsBarrier();
    }
    preloadRow<5, 5>(96, tid, Q4, r11, r01, r10);  // 32*5=160 >= 111
    fwInit<5, 5>(96, tid, r11, r01, r10, fw11, fw01, fw10);
    for (int k = 96; k < 112; ++k) {
        doStepC<5, 5>(k, tid, laneId, Q4, wsBT, v, ci, cj, cact, vL, vR,
                      r11, r01, r10, fw11, fw01, fw10);
        ldsBarrier();
    }
    preloadRow<6, 3>(112, tid, Q4, r11, r01, r10);  // 64*3=192 >= 127
    fwInit<6, 3>(112, tid, r11, r01, r10, fw11, fw01, fw10);
    for (int k = 112; k < 128; ++k) {
        doStepC<6, 3>(k, tid, laneId, Q4, wsBT, v, ci, cj, cact, vL, vR,
                      r11, r01, r10, fw11, fw01, fw10);
        ldsBarrier();
    }

    // Full barrier (drains vmcnt) before reading wsBT back.
    __syncthreads();

    // ---- epilogue: emit full [N][N][2][2] scores + backtrace, coalesced ----
    float4* gS4 = (float4*)(outS + (size_t)b * kN * kN * 4);
    float4* gB4 = (float4*)(outBT + (size_t)b * kN * kN * 4);
    const float4 negq = make_float4(kNeg, kNeg, kNeg, kNeg);
    for (int c = tid; c < kN * kN; c += kThreads) {
        const int i = c >> 7, j = c & (kN - 1);
        if (i < j) {
            const float4 q = Q4[colBaseD(j) + i];
            gS4[c] = make_float4(q.x, q.z, q.w, q.y);  // {s00, s01, s10, s11}
            const uint32_t p = wsBT[rowBase(i) + (j - i - 1)];
            gB4[c] = make_float4((float)(p & 255u), (float)((p >> 8) & 255u),
                                 (float)((p >> 16) & 255u), (float)(p >> 24));
        } else if (i == j) {
            gS4[c] = zeroq;
            gB4[c] = zeroq;
        } else {
            gS4[c] = negq;
            gB4[c] = zeroq;
        }
    }
}

extern "C" void kernel_launch(void* const* d_in, const int* in_sizes, int n_in,
                              void* d_out, int out_size, void* d_ws, size_t ws_size,
                              hipStream_t stream) {
    (void)n_in; (void)out_size; (void)ws_size;
    const float* vinfo = (const float*)d_in[0];  // fp32 [B][N][N]
    const int B = in_sizes[1];                   // b_buffer_size has B elements
    float* outS = (float*)d_out;
    float* outBT = outS + (size_t)B * kN * kN * 4;
    uint32_t* btPacked = (uint32_t*)d_ws;        // needs B*kTri*4 = ~2.1 MB

    hipFuncSetAttribute(reinterpret_cast<const void*>(eisner_dp),
                        hipFuncAttributeMaxDynamicSharedMemorySize, kDynLds);

    eisner_dp<<<dim3(B), dim3(kThreads), kDynLds, stream>>>(vinfo, outS, outBT, btPacked);
}

// Round 4
// 236.380 us; speedup vs baseline: 1.1733x; 1.0359x over previous
//
#include <hip/hip_runtime.h>
#include <stdint.h>

static constexpr int kN = 128;
static constexpr int kTri = (kN * (kN - 1)) / 2;   // 8128 (BT scratch indexing)
static constexpr int kTriD = (kN * (kN + 1)) / 2;  // 8256 cells incl. diagonal
static constexpr int kThreads = 1024;
static constexpr float kNeg = -9999.0f;
static constexpr float kThresh = -9000.0f;
static constexpr float kArcBonus = 5.0f;
static constexpr int kDynLds = kTriD * 16;  // 132,096 B (one float4 quad per cell)
static constexpr int kCMax = 9;             // max row-cache slots per lane

__device__ __forceinline__ int rowBase(int i) { return (i * (2 * kN - 1 - i)) / 2; }
__device__ __forceinline__ int colBaseD(int c) { return (c * (c + 1)) / 2; }  // cells (r<=c, c)

// LDS-only workgroup barrier: orders LDS without draining vmcnt (wsBT stores
// and vL/vR prefetch loads stay in flight across steps).
__device__ __forceinline__ void ldsBarrier() {
    asm volatile("s_waitcnt lgkmcnt(0)\n\ts_barrier" ::: "memory");
}

// DPP cross-lane reduce helpers -- pure VALU, never touch the LDS pipe.
// Ctrl sequence 0xB1 (xor1), 0x4E (xor2), 0x141 (half-mirror -> 8 lanes),
// 0x140 (row-mirror -> 16 lanes). All source lanes are exec-enabled (the
// reduction runs under wave-uniform waveActive), so bound_ctrl never kicks in.
template <int CTRL>
__device__ __forceinline__ float dppMax(float x) {
    const int y = __builtin_amdgcn_update_dpp(__float_as_int(x), __float_as_int(x),
                                              CTRL, 0xF, 0xF, true);
    return fmaxf(x, __int_as_float(y));
}
template <int CTRL>
__device__ __forceinline__ int dppMinI(int x) {
    const int y = __builtin_amdgcn_update_dpp(x, x, CTRL, 0xF, 0xF, true);
    return (y < x) ? y : x;
}

// Static phase schedule (kN=128, 1024 threads): serial k<=16; P=8 k in
// [17,63]; P=16 [64,127]. P capped at 16 so all reductions are pure DPP
// (P=32/64 phases cost 6 ds_swizzle/ds_permute per wave per step on the
// shared LDS pipe -- measured dominant; see R4 notes).
__device__ __forceinline__ int lpOf(int k) {
    if (k <= 16) return 0;
    if (k < 64) return 3;
    return 4;
}
__device__ __forceinline__ void mapStatic(int nk, int tid, int& i, int& j, bool& act) {
    const int lp = lpOf(nk);
    i = tid >> lp;
    j = i + nk;
    act = i < (kN - nk);
}

// Quad per cell: {x=s00, y=s11, z=s01, w=s10}, col-major incl. diagonal (diag=0).
// Returns the stored quad so callers can mirror it into registers.
__device__ __forceinline__ float4 writeCell(float4* __restrict__ Q4,
                                            uint32_t* __restrict__ wsBT,
                                            int i, int j, int k,
                                            float gb, int ib, float vLc, float vRc,
                                            float v01, int i01, float v11, int i11) {
    const float v00 = (gb + vLc) + kArcBonus;
    const float v10 = (gb + vRc) + kArcBonus;
    const float new10 = (v10 > kThresh) ? v10 : kNeg;
    if (new10 > v11) { v11 = new10; i11 = k; }  // q=j candidate; strict > keeps earlier q
    float4 w = make_float4(kNeg, kNeg, kNeg, kNeg);
    uint32_t p = 0;
    if (v00 > kThresh) { w.x = v00; p |= (uint32_t)(i + ib); }
    if (v01 > kThresh) { w.z = v01; p |= (uint32_t)(i + i01) << 8; }
    if (v10 > kThresh) { w.w = v10; p |= (uint32_t)(i + ib) << 16; }
    if (v11 > kThresh) { w.y = v11; p |= (uint32_t)(i + i11) << 24; }
    Q4[colBaseD(j) + i] = w;          // one ds_write_b128
    wsBT[rowBase(i) + k - 1] = p;     // lone global store; not drained per step
    return w;
}

// Serial step (k<=16), k is COMPILE-TIME (caller loop unrolled): one thread per
// cell, i = tid fixed across the whole serial phase, so all row operands
// {s11,s01,s10}(i, i+m) are this thread's OWN previous outputs, mirrored in
// sr[] registers. Only the column stream (other threads' cells) reads LDS,
// with base+immediate-offset addressing.
__device__ __forceinline__ void doStepSerialReg(int k, int tid,
                                                float4* __restrict__ Q4,
                                                uint32_t* __restrict__ wsBT,
                                                const float* __restrict__ v,
                                                int& ci, int& cj, bool& cact,
                                                float& vL, float& vR,
                                                float (&sr11)[17], float (&sr01)[17],
                                                float (&sr10)[17]) {
    const int i = ci, j = cj;
    const bool act = cact;
    const float vLc = vL, vRc = vR;
    float bmax = -3.0e38f, v01 = -3.0e38f, v11 = -3.0e38f;
    int ib = 0, i01 = 0, i11 = 0x7FFFFFFF;
    if (act) {
        const int qjb = colBaseD(j);
        float4 cur = Q4[qjb + i + 1];  // quad(i+1, j); diagonal zeros when k==1
        bmax = cur.z; ib = 0;          // base(0) = 0 + s01[i+1][j]
        const float p00 = (cur.z + vLc) + kArcBonus;
        v01 = (p00 > kThresh) ? p00 : kNeg; i01 = 0;  // part00 seed
#pragma unroll
        for (int m = 1; m < 16; ++m) {
            if (m < k) {  // compile-time when k is constant-folded
                const float4 nxt = Q4[qjb + i + m + 1];  // quad(q+1, j)
                const float base = sr11[m] + nxt.z;      // s11[i][q] + s01[q+1][j]
                const float p01v = sr01[m] + cur.x;      // s01[i][q] + s00[q][j]
                const float p11v = sr10[m] + cur.y;      // s10[i][q] + s11[q][j]
                if (base > bmax) { bmax = base; ib = m; }  // strict > keeps earliest m
                if (p01v > v01) { v01 = p01v; i01 = m; }
                if (p11v > v11) { v11 = p11v; i11 = m; }
                cur = nxt;
            }
        }
    }
    if (k + 1 < kN) {
        mapStatic(k + 1, tid, ci, cj, cact);
        vL = cact ? v[cj * kN + ci] : 0.f;
        vR = cact ? v[ci * kN + cj] : 0.f;
    }
    if (act) {
        const float4 w = writeCell(Q4, wsBT, i, j, k, bmax, ib, vLc, vRc,
                                   v01, i01, v11, i11);
        sr11[k] = w.y; sr01[k] = w.z; sr10[k] = w.w;  // constant index (k unrolled)
    }
}

// ---- Chunked phases: register row-cache + fw forwarding ----
// Within a phase, i = tid>>LP is FIXED and chart cells are write-once.
//  * Row operands {s11,s01,s10}(i, i+m): preloaded once per phase into r[].
//  * The fresh slot m = k-1 is the cell THIS group computed last step: after
//    the butterfly every lane holds the group max, so it lives in registers
//    (fw11/fw01/fw10). ZERO row LDS reads in steady state.
//  * Column stream: chained reads guarded by m < mhi (verified structure).
template <int LP, int C>
__device__ __forceinline__ void preloadRow(int k0, int tid,
                                           const float4* __restrict__ Q4,
                                           float (&r11)[kCMax], float (&r01)[kCMax],
                                           float (&r10)[kCMax]) {
    constexpr int P = 1 << LP;
    const int i = tid >> LP;
    const int l = tid & (P - 1);
    const int mlo = l * C;
    const int mstart = mlo ? mlo : 1;
    const bool act = i < (kN - k0);
#pragma unroll
    for (int c = 0; c < C; ++c) {
        const int m = mstart + c;
        if (act && (m < mlo + C) && (m <= k0 - 1)) {  // incl. m=k0-1 (visible here)
            const float4 d = Q4[colBaseD(i + m) + i];  // quad(i, i+m), immutable
            r11[c] = d.y; r01[c] = d.z; r10[c] = d.w;
        }
    }
    // Slots with m > k0-1 stay stale: first read only at step k=m+1, where the
    // isF path substitutes fw and commits it -- stale value never consumed.
}

// Seed fw from the preloaded row slot m = k0-1 (only the owning lane's fw
// matters at the first step of a phase).
template <int LP, int C>
__device__ __forceinline__ void fwInit(int k0, int tid,
                                       const float (&r11)[kCMax], const float (&r01)[kCMax],
                                       const float (&r10)[kCMax],
                                       float& fw11, float& fw01, float& fw10) {
    constexpr int P = 1 << LP;
    const int l = tid & (P - 1);
    const int mlo = l * C;
    const int mstart = mlo ? mlo : 1;
#pragma unroll
    for (int c = 0; c < C; ++c) {
        if (mstart + c == k0 - 1) { fw11 = r11[c]; fw01 = r01[c]; fw10 = r10[c]; }
    }
}

template <int LP, int C>
__device__ __forceinline__ void doStepC(int k, int tid,
                                        float4* __restrict__ Q4,
                                        uint32_t* __restrict__ wsBT,
                                        const float* __restrict__ v,
                                        int& ci, int& cj, bool& cact,
                                        float& vL, float& vR,
                                        float (&r11)[kCMax], float (&r01)[kCMax],
                                        float (&r10)[kCMax],
                                        float& fw11, float& fw01, float& fw10) {
    constexpr int P = 1 << LP;
    static_assert(P <= 16, "reductions must stay pure-DPP");
    const int i = ci, j = cj;
    const bool act = cact;
    const float vLc = vL, vRc = vR;  // prefetch below overwrites vL/vR
    const int l = tid & (P - 1);
    const int mlo = l * C;
    const int mstart = mlo ? mlo : 1;
    const int mhi = (mlo + C < k) ? (mlo + C) : k;
    const bool waveActive = (((tid & ~63) >> LP) < (kN - k));  // wave-uniform

    float bmax = -3.0e38f, v01 = -3.0e38f, v11 = -3.0e38f;
    int ib = 0x7FFFFFFF, i01 = 0x7FFFFFFF, i11 = 0x7FFFFFFF;

    const int mf = k - 1;
    const bool lact = waveActive && act && (mstart < mhi);
    const int qjb = colBaseD(j);
    float4 cur = make_float4(0.f, 0.f, 0.f, 0.f);
    if (lact) cur = Q4[qjb + i + mstart];  // column seed quad(i+mstart, j)
    if (act && mlo == 0) {
        bmax = cur.z; ib = 0;  // base(0) = 0 + s01[i+1][j]
        const float p00 = (cur.z + vLc) + kArcBonus;
        v01 = (p00 > kThresh) ? p00 : kNeg; i01 = 0;  // part00 seed
    }
#pragma unroll
    for (int c = 0; c < C; ++c) {
        const int m = mstart + c;
        // Row operands: registers; fresh slot m==k-1 comes from fw (the cell
        // this group computed last step), committed into the cache here.
        const bool isF = (m == mf);
        const float a11 = isF ? fw11 : r11[c];
        const float a01 = isF ? fw01 : r01[c];
        const float a10 = isF ? fw10 : r10[c];
        r11[c] = a11; r01[c] = a01; r10[c] = a10;
        const bool on = lact && (m < mhi);
        if (on) {
            const float4 nxt = Q4[qjb + i + m + 1];  // quad(q+1, j); compile-time offset
            const float base = a11 + nxt.z;          // s11[i][q] + s01[q+1][j]
            const float p01v = a01 + cur.x;          // s01[i][q] + s00[q][j]
            const float p11v = a10 + cur.y;          // s10[i][q] + s11[q][j]
            if (base > bmax) { bmax = base; ib = m; }  // strict > keeps earliest m
            if (p01v > v01) { v01 = p01v; i01 = m; }
            if (p11v > v11) { v11 = p11v; i11 = m; }
            cur = nxt;
        }
    }

    // Prefetch next step's mapping + vL/vR (overlaps reduction + barrier).
    if (k + 1 < kN) {
        mapStatic(k + 1, tid, ci, cj, cact);
        vL = cact ? v[cj * kN + ci] : 0.f;
        vR = cact ? v[ci * kN + cj] : 0.f;
    }

    if (waveActive) {
        // Value butterfly (pure DPP, VALU pipe only).
        float gB = dppMax<0x141>(dppMax<0x4E>(dppMax<0xB1>(bmax)));
        float g01 = dppMax<0x141>(dppMax<0x4E>(dppMax<0xB1>(v01)));
        float g11 = dppMax<0x141>(dppMax<0x4E>(dppMax<0xB1>(v11)));
        if constexpr (P == 16) {
            gB = dppMax<0x140>(gB); g01 = dppMax<0x140>(g01); g11 = dppMax<0x140>(g11);
        }
        // Earliest-m argmax: mask losers to INT_MAX, min-butterfly (pure DPP).
        // Chunks are lane-ordered and within-lane strict-> keeps the earliest
        // m, so min over tied lanes == global earliest m. Empty/inactive lanes
        // hold -3e38 which can never equal the group max (lane l==0 always
        // seeds a real value), so their mask is INT_MAX.
        int cB = (bmax == gB) ? ib : 0x7FFFFFFF;
        int c01 = (v01 == g01) ? i01 : 0x7FFFFFFF;
        int c11 = (v11 == g11) ? i11 : 0x7FFFFFFF;
        cB = dppMinI<0x141>(dppMinI<0x4E>(dppMinI<0xB1>(cB)));
        c01 = dppMinI<0x141>(dppMinI<0x4E>(dppMinI<0xB1>(c01)));
        c11 = dppMinI<0x141>(dppMinI<0x4E>(dppMinI<0xB1>(c11)));
        if constexpr (P == 16) {
            cB = dppMinI<0x140>(cB); c01 = dppMinI<0x140>(c01); c11 = dppMinI<0x140>(c11);
        }

        // All lanes now hold the group's written-cell values: keep the row-
        // operand triple in registers for next step's fresh slot (m = k).
        // Identical arithmetic to writeCell => bitwise-equal values.
        const float v10f = (gB + vRc) + kArcBonus;
        const float new10 = (v10f > kThresh) ? v10f : kNeg;
        float v11m = g11;
        if (new10 > v11m) v11m = new10;
        fw11 = (v11m > kThresh) ? v11m : kNeg;  // w.y = s11(i,j)
        fw01 = (g01 > kThresh) ? g01 : kNeg;    // w.z = s01(i,j)
        fw10 = (v10f > kThresh) ? v10f : kNeg;  // w.w = s10(i,j)

        if (act && l == 0) {
            writeCell(Q4, wsBT, i, j, k, gB, cB, vLc, vRc, g01, c01, g11, c11);
        }
    }
}

__global__ __launch_bounds__(kThreads) void eisner_dp(
    const float* __restrict__ vinfo,  // [B][N][N] fp32
    float* __restrict__ outS,         // [B][N][N][2][2] fp32 scores
    float* __restrict__ outBT,        // [B][N][N][2][2] fp32 backtrace (integer-valued)
    uint32_t* __restrict__ btPacked)  // [B][kTri] packed backtrace bytes (d_ws)
{
    extern __shared__ float4 Q4[];

    const int tid = threadIdx.x;
    const int b = blockIdx.x;
    const float* v = vinfo + (size_t)b * kN * kN;
    uint32_t* wsBT = btPacked + (size_t)b * kTri;

    // Diagonal quads = 0. Off-diagonal cells need no init (written before read).
    const float4 zeroq = make_float4(0.f, 0.f, 0.f, 0.f);
    if (tid < kN) Q4[colBaseD(tid) + tid] = zeroq;

    // Prefetch step-1 mapping + vL/vR.
    int ci, cj; bool cact;
    mapStatic(1, tid, ci, cj, cact);
    float vL = cact ? v[cj * kN + ci] : 0.f;
    float vR = cact ? v[ci * kN + cj] : 0.f;
    __syncthreads();

    // ---- serial phase (k = 1..16), fully unrolled so sr indices are constant;
    // own-row operands live entirely in registers ----
    {
        float sr11[17], sr01[17], sr10[17];
#pragma unroll
        for (int k = 1; k <= 16; ++k) {
            doStepSerialReg(k, tid, Q4, wsBT, v, ci, cj, cact, vL, vR,
                            sr11, sr01, sr10);
            ldsBarrier();
        }
    }

    // Row caches (registers); slots filled by preloadRow + fw commits.
    float r11[kCMax], r01[kCMax], r10[kCMax];
    float fw11 = kNeg, fw01 = kNeg, fw10 = kNeg;
#pragma unroll
    for (int c = 0; c < kCMax; ++c) { r11[c] = kNeg; r01[c] = kNeg; r10[c] = kNeg; }

    // P=8 phase split: C=5 while k<40 (8*5=40 >= 39), C=9 after (72 >= 63).
    preloadRow<3, 5>(17, tid, Q4, r11, r01, r10);
    fwInit<3, 5>(17, tid, r11, r01, r10, fw11, fw01, fw10);
    for (int k = 17; k < 40; ++k) {
        doStepC<3, 5>(k, tid, Q4, wsBT, v, ci, cj, cact, vL, vR,
                      r11, r01, r10, fw11, fw01, fw10);
        ldsBarrier();
    }
    preloadRow<3, 9>(40, tid, Q4, r11, r01, r10);
    fwInit<3, 9>(40, tid, r11, r01, r10, fw11, fw01, fw10);
    for (int k = 40; k < 64; ++k) {
        doStepC<3, 9>(k, tid, Q4, wsBT, v, ci, cj, cact, vL, vR,
                      r11, r01, r10, fw11, fw01, fw10);
        ldsBarrier();
    }
    // P=16 phases replace the old P=32/64 tail: pure-DPP reductions, far
    // fewer active waves issuing LDS ops. C=7: 16*7=112 >= 111; C=9: 144>=127.
    preloadRow<4, 7>(64, tid, Q4, r11, r01, r10);
    fwInit<4, 7>(64, tid, r11, r01, r10, fw11, fw01, fw10);
    for (int k = 64; k < 112; ++k) {
        doStepC<4, 7>(k, tid, Q4, wsBT, v, ci, cj, cact, vL, vR,
                      r11, r01, r10, fw11, fw01, fw10);
        ldsBarrier();
    }
    preloadRow<4, 9>(112, tid, Q4, r11, r01, r10);
    fwInit<4, 9>(112, tid, r11, r01, r10, fw11, fw01, fw10);
    for (int k = 112; k < 128; ++k) {
        doStepC<4, 9>(k, tid, Q4, wsBT, v, ci, cj, cact, vL, vR,
                      r11, r01, r10, fw11, fw01, fw10);
        ldsBarrier();
    }

    // Full barrier (drains vmcnt) before reading wsBT back.
    __syncthreads();

    // ---- epilogue: emit full [N][N][2][2] scores + backtrace, coalesced ----
    float4* gS4 = (float4*)(outS + (size_t)b * kN * kN * 4);
    float4* gB4 = (float4*)(outBT + (size_t)b * kN * kN * 4);
    const float4 negq = make_float4(kNeg, kNeg, kNeg, kNeg);
    for (int c = tid; c < kN * kN; c += kThreads) {
        const int i = c >> 7, j = c & (kN - 1);
        if (i < j) {
            const float4 q = Q4[colBaseD(j) + i];
            gS4[c] = make_float4(q.x, q.z, q.w, q.y);  // {s00, s01, s10, s11}
            const uint32_t p = wsBT[rowBase(i) + (j - i - 1)];
            gB4[c] = make_float4((float)(p & 255u), (float)((p >> 8) & 255u),
                                 (float)((p >> 16) & 255u), (float)(p >> 24));
        } else if (i == j) {
            gS4[c] = zeroq;
            gB4[c] = zeroq;
        } else {
            gS4[c] = negq;
            gB4[c] = zeroq;
        }
    }
}

extern "C" void kernel_launch(void* const* d_in, const int* in_sizes, int n_in,
                              void* d_out, int out_size, void* d_ws, size_t ws_size,
                              hipStream_t stream) {
    (void)n_in; (void)out_size; (void)ws_size;
    const float* vinfo = (const float*)d_in[0];  // fp32 [B][N][N]
    const int B = in_sizes[1];                   // b_buffer_size has B elements
    float* outS = (float*)d_out;
    float* outBT = outS + (size_t)B * kN * kN * 4;
    uint32_t* btPacked = (uint32_t*)d_ws;        // needs B*kTri*4 = ~2.1 MB

    hipFuncSetAttribute(reinterpret_cast<const void*>(eisner_dp),
                        hipFuncAttributeMaxDynamicSharedMemorySize, kDynLds);

    eisner_dp<<<dim3(B), dim3(kThreads), kDynLds, stream>>>(vinfo, outS, outBT, btPacked);
}